// Round 5
// baseline (921.542 us; speedup 1.0000x reference)
//
#include <hip/hip_runtime.h>
#include <hip/hip_bf16.h>

// HGNN: out = BN(ReLU( segmax( BN(ReLU(concat(lf[li], dcoor) @ W1 + b1)) ) @ W2 + b2))
//   G[n,f]  = (last_features @ W1[:300] + b1)  as bf16 [N_last][320] padded (MFMA GEMM)
//   y[e,f]  = ReLU(G[li[e],f] + delta[e] . Wc[:,f])   (edge pass, bf16x8 chunks)
//   Edges counting-sorted by cur_idx; per-wave serial walk of 64 sorted edges,
//   8-feature chunks per lane (one 16B load/edge), register running max,
//   atomicMax flush (order-preserving uint encoding) at segment boundaries.
//   BN1 affine a*y+c, sign(a)=sign(g1) known upfront; encoded-0 => empty => 0.
//   out_pre = ReLU(agg @ W2 + b2) -> d_out (MFMA GEMM, stats fused), affine in place.
// Workspace aliasing: region1 = Alf (bf16 A gemm0) then zbuf; region0 = Gb then Ab2.

#define NPART 64
#define SB 256      // scan block
#define CH 256      // edges per edge_pass block (64 per wave)

typedef __bf16 bf16_t;
typedef __bf16 bf16x4 __attribute__((ext_vector_type(4)));
typedef __bf16 bf16x8 __attribute__((ext_vector_type(8)));
typedef float f32x4 __attribute__((ext_vector_type(4)));

__device__ __forceinline__ unsigned enc_f32(float x) {
    unsigned u = __float_as_uint(x);
    return (u & 0x80000000u) ? ~u : (u | 0x80000000u);
}
__device__ __forceinline__ float dec_f32(unsigned e) {
    unsigned u = (e & 0x80000000u) ? (e & 0x7fffffffu) : ~e;
    return __uint_as_float(u);
}

// ---------- counting sort: hist -> scan -> scatter ----------
__global__ void hist_k(const int* __restrict__ ci, int E, int* __restrict__ hist)
{
    const int e = blockIdx.x * 256 + threadIdx.x;
    if (e < E) atomicAdd(&hist[ci[e]], 1);
}

__global__ void scan_reduce(const int* __restrict__ hist, int nseg, int* __restrict__ bsum)
{
    __shared__ int s[SB];
    const int tid = threadIdx.x;
    const int i = blockIdx.x * SB + tid;
    s[tid] = (i < nseg) ? hist[i] : 0;
    __syncthreads();
    for (int o = SB / 2; o > 0; o >>= 1) {
        if (tid < o) s[tid] += s[tid + o];
        __syncthreads();
    }
    if (tid == 0) bsum[blockIdx.x] = s[0];
}

__global__ void scan_top(int* __restrict__ bsum, int nb)
{
    __shared__ int s[SB];
    const int tid = threadIdx.x;
    const int v = (tid < nb) ? bsum[tid] : 0;
    s[tid] = v;
    __syncthreads();
    for (int o = 1; o < SB; o <<= 1) {
        int x = 0;
        if (tid >= o) x = s[tid - o];
        __syncthreads();
        s[tid] += x;
        __syncthreads();
    }
    if (tid < nb) bsum[tid] = s[tid] - v;   // exclusive
}

__global__ void scan_final(const int* __restrict__ hist, int nseg,
                           const int* __restrict__ bsum, int* __restrict__ cnt)
{
    __shared__ int s[SB];
    const int tid = threadIdx.x;
    const int i = blockIdx.x * SB + tid;
    const int v = (i < nseg) ? hist[i] : 0;
    s[tid] = v;
    __syncthreads();
    for (int o = 1; o < SB; o <<= 1) {
        int x = 0;
        if (tid >= o) x = s[tid - o];
        __syncthreads();
        s[tid] += x;
        __syncthreads();
    }
    if (i < nseg) cnt[i] = s[tid] - v + bsum[blockIdx.x];
}

__global__ void scatter_k(const int* __restrict__ ci, const int* __restrict__ li,
                          int E, int* __restrict__ cnt, int2* __restrict__ sorted)
{
    const int e = blockIdx.x * 256 + threadIdx.x;
    if (e >= E) return;
    const int c = ci[e];
    const int pos = atomicAdd(&cnt[c], 1);
    sorted[pos] = make_int2(li[e], c);
}

// ---------- pack W (fp32 [300][300] row-major) -> WT bf16 [384][320] = [n][k] ----------
__global__ void pack_wt(const float* __restrict__ W, bf16_t* __restrict__ WT)
{
    const int idx = blockIdx.x * 256 + threadIdx.x;
    if (idx >= 384 * 320) return;
    const int n = idx / 320, k = idx % 320;
    float v = (n < 300 && k < 300) ? W[k * 300 + n] : 0.f;
    WT[idx] = (bf16_t)v;
}

// ---------- convert lf fp32 [M][300] -> bf16 [M][320] zero-padded ----------
__global__ void cvt_lf(const float* __restrict__ lf, bf16_t* __restrict__ out, int M)
{
    const int idx = blockIdx.x * 256 + threadIdx.x;
    const int r = idx / 40, c8 = (idx % 40) * 8;
    if (r >= M) return;
    bf16x8 v = {};
    if (c8 + 8 <= 300) {
        const float4 a = *reinterpret_cast<const float4*>(&lf[(long)r * 300 + c8]);
        const float4 b = *reinterpret_cast<const float4*>(&lf[(long)r * 300 + c8 + 4]);
        v = (bf16x8){(bf16_t)a.x, (bf16_t)a.y, (bf16_t)a.z, (bf16_t)a.w,
                     (bf16_t)b.x, (bf16_t)b.y, (bf16_t)b.z, (bf16_t)b.w};
    } else if (c8 < 300) {   // c8 == 296
        const float4 a = *reinterpret_cast<const float4*>(&lf[(long)r * 300 + c8]);
        v[0] = (bf16_t)a.x; v[1] = (bf16_t)a.y; v[2] = (bf16_t)a.z; v[3] = (bf16_t)a.w;
    }
    *reinterpret_cast<bf16x8*>(&out[(long)r * 320 + c8]) = v;
}

// ---------- MFMA bf16 GEMM ----------
// A bf16 [M][320] zero-padded; WT bf16 [384][320] = [n][k].
// Tiles: 128 (M) x 160 (N), BK=64; 4 waves 2x2.
// MODE 0: store bf16 [M][320] (incl. zero pad cols). MODE 1: ReLU, fp32 [M][300], stats.
template<int MODE>
__launch_bounds__(256)
__global__ void gemm_mfma(const bf16_t* __restrict__ A, int M,
                          const bf16_t* __restrict__ WT,
                          const float* __restrict__ bias,
                          bf16_t* __restrict__ outBF,
                          float* __restrict__ outF,
                          float* __restrict__ part)
{
    __shared__ bf16_t As[128][72];
    __shared__ bf16_t Bs[160][72];
    __shared__ float sSum[160], sSq[160];

    const int tid  = threadIdx.x;
    const int lane = tid & 63, wv = tid >> 6;
    const int wm = wv & 1, wn = wv >> 1;
    const int m0 = blockIdx.x * 128, n0 = blockIdx.y * 160;
    const int rl = lane & 15, quad = lane >> 4;

    if (MODE == 1 && tid < 160) { sSum[tid] = 0.f; sSq[tid] = 0.f; }

    f32x4 acc[4][5];
    #pragma unroll
    for (int i = 0; i < 4; ++i)
        #pragma unroll
        for (int j = 0; j < 5; ++j)
            acc[i][j] = (f32x4){0.f, 0.f, 0.f, 0.f};

    for (int k0 = 0; k0 < 320; k0 += 64) {
        #pragma unroll
        for (int i = 0; i < 4; ++i) {
            const int id = i * 256 + tid;
            const int r = id >> 3, kc = (id & 7) * 8;
            const int gr = min(m0 + r, M - 1);
            bf16x8 a8 = *reinterpret_cast<const bf16x8*>(&A[(long)gr * 320 + k0 + kc]);
            *reinterpret_cast<bf16x8*>(&As[r][kc]) = a8;
        }
        #pragma unroll
        for (int i = 0; i < 5; ++i) {
            const int id = i * 256 + tid;
            const int n = id >> 3, kc = (id & 7) * 8;
            bf16x8 w8 = *reinterpret_cast<const bf16x8*>(&WT[(long)(n0 + n) * 320 + k0 + kc]);
            *reinterpret_cast<bf16x8*>(&Bs[n][kc]) = w8;
        }
        __syncthreads();

        #pragma unroll
        for (int kk = 0; kk < 2; ++kk) {
            const int kb = kk * 32 + quad * 8;
            bf16x8 af[4], bfr[5];
            #pragma unroll
            for (int mi = 0; mi < 4; ++mi)
                af[mi] = *reinterpret_cast<const bf16x8*>(&As[wm * 64 + mi * 16 + rl][kb]);
            #pragma unroll
            for (int nj = 0; nj < 5; ++nj)
                bfr[nj] = *reinterpret_cast<const bf16x8*>(&Bs[wn * 80 + nj * 16 + rl][kb]);
            #pragma unroll
            for (int mi = 0; mi < 4; ++mi)
                #pragma unroll
                for (int nj = 0; nj < 5; ++nj)
                    acc[mi][nj] = __builtin_amdgcn_mfma_f32_16x16x32_bf16(
                        af[mi], bfr[nj], acc[mi][nj], 0, 0, 0);
        }
        __syncthreads();
    }

    // epilogue: C/D layout col = lane&15, row = quad*4 + reg
    if (MODE == 0) {
        #pragma unroll
        for (int mi = 0; mi < 4; ++mi)
            #pragma unroll
            for (int nj = 0; nj < 5; ++nj)
                #pragma unroll
                for (int reg = 0; reg < 4; ++reg) {
                    const int r = m0 + wm * 64 + mi * 16 + quad * 4 + reg;
                    const int c = n0 + wn * 80 + nj * 16 + rl;
                    if (r < M && c < 320) {
                        const float bv = (c < 300) ? bias[c] : 0.f;  // acc=0 in pad cols
                        outBF[(long)r * 320 + c] = (bf16_t)(acc[mi][nj][reg] + bv);
                    }
                }
    } else {
        float csum[5] = {}, csq[5] = {};
        #pragma unroll
        for (int mi = 0; mi < 4; ++mi)
            #pragma unroll
            for (int nj = 0; nj < 5; ++nj)
                #pragma unroll
                for (int reg = 0; reg < 4; ++reg) {
                    const int r = m0 + wm * 64 + mi * 16 + quad * 4 + reg;
                    const int c = n0 + wn * 80 + nj * 16 + rl;
                    if (r < M && c < 300) {
                        float v = fmaxf(acc[mi][nj][reg] + bias[c], 0.f);
                        outF[(long)r * 300 + c] = v;
                        csum[nj] += v; csq[nj] += v * v;
                    }
                }
        #pragma unroll
        for (int nj = 0; nj < 5; ++nj) {
            const int cl = wn * 80 + nj * 16 + rl;
            atomicAdd(&sSum[cl], csum[nj]);
            atomicAdd(&sSq[cl], csq[nj]);
        }
        __syncthreads();
        const int slot = (blockIdx.x + blockIdx.y * gridDim.x) & (NPART - 1);
        if (tid < 160 && (n0 + tid) < 300) {
            atomicAdd(&part[slot * 600 + n0 + tid], sSum[tid]);
            atomicAdd(&part[slot * 600 + 300 + n0 + tid], sSq[tid]);
        }
    }
}

// ---------- edge pass: bf16x8 feature chunks, per-wave serial edge walk ----------
__launch_bounds__(256)
__global__ void edge_pass(const bf16_t* __restrict__ Gb,      // [N_last][320]
                          const float* __restrict__ last_coors,
                          const float* __restrict__ cur_coors,
                          const int2* __restrict__ sorted,    // (li, ci), sorted by ci
                          const float* __restrict__ Wc,       // rows 300..302 of W1, 3x300
                          const float* __restrict__ g1,
                          unsigned* __restrict__ zbuf,        // [N_cur][320] encoded, init 0
                          float* __restrict__ part1,          // NPART x 640
                          int E)
{
    __shared__ int sRow[CH], sCi[CH];
    __shared__ float sD0[CH], sD1[CH], sD2[CH];
    __shared__ float sSum[320], sSq[320];

    const int tid = threadIdx.x;
    const int lane = tid & 63, w = tid >> 6;

    for (int i = tid; i < 320; i += 256) { sSum[i] = 0.f; sSq[i] = 0.f; }

    const int e0 = blockIdx.x * CH;
    const int ecnt = min(CH, E - e0);

    if (tid < ecnt) {
        const int2 r = sorted[e0 + tid];
        sRow[tid] = r.x * 320;
        sCi[tid]  = r.y;
        sD0[tid] = last_coors[r.x * 3 + 0] - cur_coors[r.y * 3 + 0];
        sD1[tid] = last_coors[r.x * 3 + 1] - cur_coors[r.y * 3 + 1];
        sD2[tid] = last_coors[r.x * 3 + 2] - cur_coors[r.y * 3 + 2];
    }
    __syncthreads();

    const int chunk = lane;              // lanes 0..39 active (8 features each)
    const int wbeg = w * 64;
    int wcnt = ecnt - wbeg;
    wcnt = wcnt < 0 ? 0 : (wcnt > 64 ? 64 : wcnt);

    if (chunk < 40 && wcnt > 0) {
        const int base = chunk * 8;
        float w0[8], w1[8], w2[8], sg[8];
        #pragma unroll
        for (int c = 0; c < 8; ++c) {
            const int f = base + c;
            const bool v = (f < 300);
            w0[c] = v ? Wc[f] : 0.f;
            w1[c] = v ? Wc[300 + f] : 0.f;
            w2[c] = v ? Wc[600 + f] : 0.f;
            sg[c] = (v && g1[f] < 0.f) ? -1.f : 1.f;
        }

        int cur = sCi[wbeg];
        float m[8], sum[8] = {}, sq[8] = {};
        #pragma unroll
        for (int c = 0; c < 8; ++c) m[c] = -3.4e38f;

        int i = 0;
        for (; i + 8 <= wcnt; i += 8) {
            bf16x8 gv[8];
            #pragma unroll
            for (int j = 0; j < 8; ++j)
                gv[j] = *reinterpret_cast<const bf16x8*>(&Gb[sRow[wbeg + i + j] + base]);
            #pragma unroll
            for (int j = 0; j < 8; ++j) {
                const int e = wbeg + i + j;
                const int ci = sCi[e];
                if (ci != cur) {                 // wave-uniform branch
                    unsigned* zp = &zbuf[(long)cur * 320 + base];
                    #pragma unroll
                    for (int c = 0; c < 8; ++c) atomicMax(&zp[c], enc_f32(m[c]));
                    cur = ci;
                    #pragma unroll
                    for (int c = 0; c < 8; ++c) m[c] = -3.4e38f;
                }
                const float d0 = sD0[e], d1 = sD1[e], d2 = sD2[e];
                #pragma unroll
                for (int c = 0; c < 8; ++c) {
                    float y = (float)gv[j][c] + d0 * w0[c] + d1 * w1[c] + d2 * w2[c];
                    y = fmaxf(y, 0.f);
                    sum[c] += y; sq[c] = fmaf(y, y, sq[c]);
                    m[c] = fmaxf(m[c], sg[c] * y);
                }
            }
        }
        for (; i < wcnt; ++i) {
            const int e = wbeg + i;
            const bf16x8 gvr = *reinterpret_cast<const bf16x8*>(&Gb[sRow[e] + base]);
            const int ci = sCi[e];
            if (ci != cur) {
                unsigned* zp = &zbuf[(long)cur * 320 + base];
                #pragma unroll
                for (int c = 0; c < 8; ++c) atomicMax(&zp[c], enc_f32(m[c]));
                cur = ci;
                #pragma unroll
                for (int c = 0; c < 8; ++c) m[c] = -3.4e38f;
            }
            const float d0 = sD0[e], d1 = sD1[e], d2 = sD2[e];
            #pragma unroll
            for (int c = 0; c < 8; ++c) {
                float y = (float)gvr[c] + d0 * w0[c] + d1 * w1[c] + d2 * w2[c];
                y = fmaxf(y, 0.f);
                sum[c] += y; sq[c] = fmaf(y, y, sq[c]);
                m[c] = fmaxf(m[c], sg[c] * y);
            }
        }
        {   // final flush
            unsigned* zp = &zbuf[(long)cur * 320 + base];
            #pragma unroll
            for (int c = 0; c < 8; ++c) atomicMax(&zp[c], enc_f32(m[c]));
        }
        #pragma unroll
        for (int c = 0; c < 8; ++c) {
            atomicAdd(&sSum[base + c], sum[c]);
            atomicAdd(&sSq[base + c], sq[c]);
        }
    }
    __syncthreads();

    const int slot = blockIdx.x & (NPART - 1);
    for (int f = tid; f < 320; f += 256) {
        atomicAdd(&part1[slot * 640 + f], sSum[f]);
        atomicAdd(&part1[slot * 640 + 320 + f], sSq[f]);
    }
}

// ---------- reduce partials -> per-feature affine (a, c) ----------
__global__ void stats_finalize(const float* __restrict__ part, int stride, int sqoff,
                               const float* __restrict__ g,
                               const float* __restrict__ be,
                               float invCnt, float* __restrict__ ac)
{
    const int t = threadIdx.x;
    if (t >= 300) return;
    float sum = 0.f, sq = 0.f;
    for (int p = 0; p < NPART; ++p) {
        sum += part[p * stride + t];
        sq  += part[p * stride + sqoff + t];
    }
    const float mean = sum * invCnt;
    const float var = fmaxf(sq * invCnt - mean * mean, 0.f);
    const float inv = rsqrtf(var + 1e-5f);
    const float a = g[t] * inv;
    ac[t] = a;
    ac[300 + t] = be[t] - mean * a;
}

// ---------- decode zbuf [N_cur][320] -> Ab2 bf16 [N_cur][320] ----------
__global__ void agg_finalize(const unsigned* __restrict__ zbuf,
                             const float* __restrict__ ac1,
                             bf16_t* __restrict__ Ab2)
{
    const int t = threadIdx.x;   // 320 threads
    float v = 0.f;
    if (t < 300) {
        const unsigned u = zbuf[(long)blockIdx.x * 320 + t];
        if (u != 0u) v = fabsf(ac1[t]) * dec_f32(u) + ac1[300 + t];
    }
    Ab2[(long)blockIdx.x * 320 + t] = (bf16_t)v;
}

// ---------- apply BN2 affine to d_out in place ----------
__global__ void finalize_out(float* __restrict__ out,
                             const float* __restrict__ ac2)
{
    const int t = threadIdx.x;
    if (t >= 300) return;
    const long i = (long)blockIdx.x * 300 + t;
    out[i] = ac2[t] * out[i] + ac2[300 + t];
}

extern "C" void kernel_launch(void* const* d_in, const int* in_sizes, int n_in,
                              void* d_out, int out_size, void* d_ws, size_t ws_size,
                              hipStream_t stream)
{
    const float* last_coors    = (const float*)d_in[0];
    const float* last_features = (const float*)d_in[1];
    const float* cur_coors     = (const float*)d_in[2];
    const int*   cur_idx       = (const int*)d_in[3];
    const int*   last_idx      = (const int*)d_in[4];
    const float* W1  = (const float*)d_in[5];
    const float* b1  = (const float*)d_in[6];
    const float* g1  = (const float*)d_in[7];
    const float* be1 = (const float*)d_in[8];
    const float* W2  = (const float*)d_in[9];
    const float* b2  = (const float*)d_in[10];
    const float* g2  = (const float*)d_in[11];
    const float* be2 = (const float*)d_in[12];
    float* out = (float*)d_out;

    const int N_last = in_sizes[0] / 3;
    const int N_cur  = in_sizes[2] / 3;
    const int E      = in_sizes[3];

    const int nb1 = (N_cur + SB - 1) / SB;

    // ---- workspace (aliased regions) ----
    char* ws = (char*)d_ws;
    size_t off = 0;
    // region0: Gb (N_last x 320 bf16) -> later Ab2 (N_cur x 320 bf16)
    bf16_t* Gb  = (bf16_t*)(ws + off);
    bf16_t* Ab2 = (bf16_t*)(ws + off);
    off += (size_t)N_last * 320 * 2; off = (off + 255) & ~(size_t)255;
    // region1: Alf (N_last x 320 bf16) -> later zbuf (N_cur x 320 u32)
    const size_t sz_alf = (size_t)N_last * 320 * 2;
    const size_t sz_zb  = (size_t)N_cur * 320 * 4;
    bf16_t* Alf = (bf16_t*)(ws + off);
    unsigned* zbuf = (unsigned*)(ws + off);
    off += (sz_alf > sz_zb ? sz_alf : sz_zb); off = (off + 255) & ~(size_t)255;
    int2* sorted = (int2*)(ws + off);  off += (size_t)E * 8;
    int* hist = (int*)(ws + off);      off += (size_t)nb1 * SB * 4;
    int* cnt  = (int*)(ws + off);      off += (size_t)nb1 * SB * 4;
    int* bsum = (int*)(ws + off);      off += 256 * 4;
    bf16_t* WT1 = (bf16_t*)(ws + off); off += (size_t)384 * 320 * 2;
    bf16_t* WT2 = (bf16_t*)(ws + off); off += (size_t)384 * 320 * 2;
    float* part1 = (float*)(ws + off); off += (size_t)NPART * 640 * 4;
    float* part2 = (float*)(ws + off); off += (size_t)NPART * 600 * 4;
    float* ac1   = (float*)(ws + off); off += 600 * 4;
    float* ac2   = (float*)(ws + off); off += 600 * 4;

    hipMemsetAsync(hist, 0, (size_t)nb1 * SB * 4, stream);
    hipMemsetAsync(part1, 0, (size_t)NPART * 640 * 4, stream);
    hipMemsetAsync(part2, 0, (size_t)NPART * 600 * 4, stream);

    // ---- counting sort of edges by cur_idx ----
    hist_k<<<(E + 255) / 256, 256, 0, stream>>>(cur_idx, E, hist);
    scan_reduce<<<nb1, SB, 0, stream>>>(hist, N_cur, bsum);
    scan_top<<<1, SB, 0, stream>>>(bsum, nb1);
    scan_final<<<nb1, SB, 0, stream>>>(hist, N_cur, bsum, cnt);
    scatter_k<<<(E + 255) / 256, 256, 0, stream>>>(cur_idx, last_idx, E, cnt, sorted);

    // ---- weights + A conversion ----
    pack_wt<<<480, 256, 0, stream>>>(W1, WT1);
    pack_wt<<<480, 256, 0, stream>>>(W2, WT2);
    cvt_lf<<<((N_last * 40) + 255) / 256, 256, 0, stream>>>(last_features, Alf, N_last);

    // G = last_features @ W1[:300] + b1  (bf16 MFMA; reads Alf, writes Gb[.,320])
    dim3 gridG((N_last + 127) / 128, 2);
    gemm_mfma<0><<<gridG, 256, 0, stream>>>(Alf, N_last, WT1, b1, Gb, nullptr, nullptr);

    // zbuf overwrites Alf (stream-ordered after gemm0)
    hipMemsetAsync(zbuf, 0, sz_zb, stream);

    // edge pass over sorted edges
    const int nEB = (E + CH - 1) / CH;
    edge_pass<<<nEB, 256, 0, stream>>>(Gb, last_coors, cur_coors, sorted,
                                       W1 + 300 * 300, g1, zbuf, part1, E);

    stats_finalize<<<1, 320, 0, stream>>>(part1, 640, 320, g1, be1, 1.0f / (float)E, ac1);
    // Ab2 overwrites Gb (Gb consumed by edge_pass)
    agg_finalize<<<N_cur, 320, 0, stream>>>(zbuf, ac1, Ab2);

    // out_pre = ReLU(agg @ W2 + b2), stats2 partials (bf16 MFMA)
    dim3 grid2((N_cur + 127) / 128, 2);
    gemm_mfma<1><<<grid2, 256, 0, stream>>>(Ab2, N_cur, WT2, b2, nullptr, out, part2);

    stats_finalize<<<1, 320, 0, stream>>>(part2, 600, 300, g2, be2, 1.0f / (float)N_cur, ac2);
    finalize_out<<<N_cur, 320, 0, stream>>>(out, ac2);
}

// Round 6
// 755.795 us; speedup vs baseline: 1.2193x; 1.2193x over previous
//
#include <hip/hip_runtime.h>
#include <hip/hip_bf16.h>

// HGNN: out = BN(ReLU( segmax( BN(ReLU(concat(lf[li], dcoor) @ W1 + b1)) ) @ W2 + b2))
//   G[n,f]  = (last_features @ W1[:300] + b1)  as bf16 [N_last][320] (MFMA GEMM, fp32 A)
//   y[e,f]  = ReLU(G[li[e],f] + delta[e] . Wc[:,f])   (edge pass, thread=feature)
//   Edges counting-sorted by cur_idx; block walks 256 sorted edges, 8-deep load batch,
//   register running max per feature-thread, ONE contiguous atomicMax flush per
//   segment boundary (per-lane atomic loops multiply TCC writebacks ~8x — R5 lesson).
//   BN1 affine a*y+c, sign(a)=sign(g1) known upfront; encoded-0 => empty => 0.
//   out_pre = ReLU(agg @ W2 + b2) -> d_out (MFMA GEMM, bf16 A, stats fused), affine.

#define NPART 64
#define SB 256      // scan block
#define CH 256      // edges per edge_pass block
#define UNR 8       // edge_pass load batch depth

typedef __bf16 bf16_t;
typedef __bf16 bf16x4 __attribute__((ext_vector_type(4)));
typedef __bf16 bf16x8 __attribute__((ext_vector_type(8)));
typedef float f32x4 __attribute__((ext_vector_type(4)));

__device__ __forceinline__ unsigned enc_f32(float x) {
    unsigned u = __float_as_uint(x);
    return (u & 0x80000000u) ? ~u : (u | 0x80000000u);
}
__device__ __forceinline__ float dec_f32(unsigned e) {
    unsigned u = (e & 0x80000000u) ? (e & 0x7fffffffu) : ~e;
    return __uint_as_float(u);
}

// ---------- counting sort: hist -> scan -> scatter ----------
__global__ void hist_k(const int* __restrict__ ci, int E, int* __restrict__ hist)
{
    const int e = blockIdx.x * 256 + threadIdx.x;
    if (e < E) atomicAdd(&hist[ci[e]], 1);
}

__global__ void scan_reduce(const int* __restrict__ hist, int nseg, int* __restrict__ bsum)
{
    __shared__ int s[SB];
    const int tid = threadIdx.x;
    const int i = blockIdx.x * SB + tid;
    s[tid] = (i < nseg) ? hist[i] : 0;
    __syncthreads();
    for (int o = SB / 2; o > 0; o >>= 1) {
        if (tid < o) s[tid] += s[tid + o];
        __syncthreads();
    }
    if (tid == 0) bsum[blockIdx.x] = s[0];
}

__global__ void scan_top(int* __restrict__ bsum, int nb)
{
    __shared__ int s[SB];
    const int tid = threadIdx.x;
    const int v = (tid < nb) ? bsum[tid] : 0;
    s[tid] = v;
    __syncthreads();
    for (int o = 1; o < SB; o <<= 1) {
        int x = 0;
        if (tid >= o) x = s[tid - o];
        __syncthreads();
        s[tid] += x;
        __syncthreads();
    }
    if (tid < nb) bsum[tid] = s[tid] - v;   // exclusive
}

__global__ void scan_final(const int* __restrict__ hist, int nseg,
                           const int* __restrict__ bsum, int* __restrict__ cnt)
{
    __shared__ int s[SB];
    const int tid = threadIdx.x;
    const int i = blockIdx.x * SB + tid;
    const int v = (i < nseg) ? hist[i] : 0;
    s[tid] = v;
    __syncthreads();
    for (int o = 1; o < SB; o <<= 1) {
        int x = 0;
        if (tid >= o) x = s[tid - o];
        __syncthreads();
        s[tid] += x;
        __syncthreads();
    }
    if (i < nseg) cnt[i] = s[tid] - v + bsum[blockIdx.x];
}

__global__ void scatter_k(const int* __restrict__ ci, const int* __restrict__ li,
                          int E, int* __restrict__ cnt, int2* __restrict__ sorted)
{
    const int e = blockIdx.x * 256 + threadIdx.x;
    if (e >= E) return;
    const int c = ci[e];
    const int pos = atomicAdd(&cnt[c], 1);
    sorted[pos] = make_int2(li[e], c);
}

// ---------- pack W (fp32 [300][300] row-major) -> WT bf16 [384][320] = [n][k] ----------
__global__ void pack_wt(const float* __restrict__ W, bf16_t* __restrict__ WT)
{
    const int idx = blockIdx.x * 256 + threadIdx.x;
    if (idx >= 384 * 320) return;
    const int n = idx / 320, k = idx % 320;
    float v = (n < 300 && k < 300) ? W[k * 300 + n] : 0.f;
    WT[idx] = (bf16_t)v;
}

// ---------- MFMA bf16 GEMM ----------
// MODE 0: A fp32 [M][300] (cvt in staging); store bf16 [M][320] incl pad cols.
// MODE 1: A bf16 [M][320] zero-padded; ReLU, fp32 [M][300], stats partials.
// WT bf16 [384][320] = [n][k]. Tiles: 128 (M) x 160 (N), BK=64; 4 waves 2x2.
template<int MODE>
__launch_bounds__(256)
__global__ void gemm_mfma(const void* __restrict__ Araw, int M,
                          const bf16_t* __restrict__ WT,
                          const float* __restrict__ bias,
                          bf16_t* __restrict__ outBF,
                          float* __restrict__ outF,
                          float* __restrict__ part)
{
    __shared__ bf16_t As[128][72];
    __shared__ bf16_t Bs[160][72];
    __shared__ float sSum[160], sSq[160];

    const int tid  = threadIdx.x;
    const int lane = tid & 63, wv = tid >> 6;
    const int wm = wv & 1, wn = wv >> 1;
    const int m0 = blockIdx.x * 128, n0 = blockIdx.y * 160;
    const int rl = lane & 15, quad = lane >> 4;

    if (MODE == 1 && tid < 160) { sSum[tid] = 0.f; sSq[tid] = 0.f; }

    f32x4 acc[4][5];
    #pragma unroll
    for (int i = 0; i < 4; ++i)
        #pragma unroll
        for (int j = 0; j < 5; ++j)
            acc[i][j] = (f32x4){0.f, 0.f, 0.f, 0.f};

    for (int k0 = 0; k0 < 320; k0 += 64) {
        if (MODE == 0) {
            const float* A = (const float*)Araw;   // [M][300] fp32
            #pragma unroll
            for (int i = 0; i < 8; ++i) {
                const int id = i * 256 + tid;
                const int r = id >> 4, kc = (id & 15) * 4;
                const int gr = min(m0 + r, M - 1), gk = k0 + kc;
                float4 a4 = {0.f, 0.f, 0.f, 0.f};
                if (gk < 300)   // 300%4==0: float4 chunk fully valid or not
                    a4 = *reinterpret_cast<const float4*>(&A[(long)gr * 300 + gk]);
                bf16x4 b4 = {(bf16_t)a4.x, (bf16_t)a4.y, (bf16_t)a4.z, (bf16_t)a4.w};
                *reinterpret_cast<bf16x4*>(&As[r][kc]) = b4;
            }
        } else {
            const bf16_t* A = (const bf16_t*)Araw; // [M][320] bf16, zero-padded
            #pragma unroll
            for (int i = 0; i < 4; ++i) {
                const int id = i * 256 + tid;
                const int r = id >> 3, kc = (id & 7) * 8;
                const int gr = min(m0 + r, M - 1);
                bf16x8 a8 = *reinterpret_cast<const bf16x8*>(&A[(long)gr * 320 + k0 + kc]);
                *reinterpret_cast<bf16x8*>(&As[r][kc]) = a8;
            }
        }
        #pragma unroll
        for (int i = 0; i < 5; ++i) {
            const int id = i * 256 + tid;
            const int n = id >> 3, kc = (id & 7) * 8;
            bf16x8 w8 = *reinterpret_cast<const bf16x8*>(&WT[(long)(n0 + n) * 320 + k0 + kc]);
            *reinterpret_cast<bf16x8*>(&Bs[n][kc]) = w8;
        }
        __syncthreads();

        #pragma unroll
        for (int kk = 0; kk < 2; ++kk) {
            const int kb = kk * 32 + quad * 8;
            bf16x8 af[4], bfr[5];
            #pragma unroll
            for (int mi = 0; mi < 4; ++mi)
                af[mi] = *reinterpret_cast<const bf16x8*>(&As[wm * 64 + mi * 16 + rl][kb]);
            #pragma unroll
            for (int nj = 0; nj < 5; ++nj)
                bfr[nj] = *reinterpret_cast<const bf16x8*>(&Bs[wn * 80 + nj * 16 + rl][kb]);
            #pragma unroll
            for (int mi = 0; mi < 4; ++mi)
                #pragma unroll
                for (int nj = 0; nj < 5; ++nj)
                    acc[mi][nj] = __builtin_amdgcn_mfma_f32_16x16x32_bf16(
                        af[mi], bfr[nj], acc[mi][nj], 0, 0, 0);
        }
        __syncthreads();
    }

    // epilogue: C/D layout col = lane&15, row = quad*4 + reg
    if (MODE == 0) {
        #pragma unroll
        for (int mi = 0; mi < 4; ++mi)
            #pragma unroll
            for (int nj = 0; nj < 5; ++nj)
                #pragma unroll
                for (int reg = 0; reg < 4; ++reg) {
                    const int r = m0 + wm * 64 + mi * 16 + quad * 4 + reg;
                    const int c = n0 + wn * 80 + nj * 16 + rl;
                    if (r < M && c < 320) {
                        const float bv = (c < 300) ? bias[c] : 0.f;  // acc=0 in pad cols
                        outBF[(long)r * 320 + c] = (bf16_t)(acc[mi][nj][reg] + bv);
                    }
                }
    } else {
        float csum[5] = {}, csq[5] = {};
        #pragma unroll
        for (int mi = 0; mi < 4; ++mi)
            #pragma unroll
            for (int nj = 0; nj < 5; ++nj)
                #pragma unroll
                for (int reg = 0; reg < 4; ++reg) {
                    const int r = m0 + wm * 64 + mi * 16 + quad * 4 + reg;
                    const int c = n0 + wn * 80 + nj * 16 + rl;
                    if (r < M && c < 300) {
                        float v = fmaxf(acc[mi][nj][reg] + bias[c], 0.f);
                        outF[(long)r * 300 + c] = v;
                        csum[nj] += v; csq[nj] += v * v;
                    }
                }
        #pragma unroll
        for (int nj = 0; nj < 5; ++nj) {
            const int cl = wn * 80 + nj * 16 + rl;
            atomicAdd(&sSum[cl], csum[nj]);
            atomicAdd(&sSq[cl], csq[nj]);
        }
        __syncthreads();
        const int slot = (blockIdx.x + blockIdx.y * gridDim.x) & (NPART - 1);
        if (tid < 160 && (n0 + tid) < 300) {
            atomicAdd(&part[slot * 600 + n0 + tid], sSum[tid]);
            atomicAdd(&part[slot * 600 + 300 + n0 + tid], sSq[tid]);
        }
    }
}

// ---------- edge pass over SORTED edges: batched loads + register running-max ----------
// thread = feature (300 active of 320); ONE atomic per thread per segment flush.
__launch_bounds__(320)
__global__ void edge_pass(const bf16_t* __restrict__ Gb,      // [N_last][320]
                          const float* __restrict__ last_coors,
                          const float* __restrict__ cur_coors,
                          const int2* __restrict__ sorted,    // (li, ci), sorted by ci
                          const float* __restrict__ Wc,       // rows 300..302 of W1, 3x300
                          const float* __restrict__ g1,
                          unsigned* __restrict__ zbuf,        // [N_cur][300] encoded, init 0
                          float* __restrict__ part1,          // NPART x 600
                          int E)
{
    __shared__ float sWc0[300], sWc1[300], sWc2[300];
    __shared__ int sRow[CH], sCi[CH];
    __shared__ float sD0[CH], sD1[CH], sD2[CH];

    const int tid = threadIdx.x;
    for (int i = tid; i < 300; i += 320) {
        sWc0[i] = Wc[i]; sWc1[i] = Wc[300 + i]; sWc2[i] = Wc[600 + i];
    }

    const int e0 = blockIdx.x * CH;
    const int ecnt = min(CH, E - e0);

    for (int i = tid; i < ecnt; i += 320) {
        const int2 r = sorted[e0 + i];
        sRow[i] = r.x * 320;
        sCi[i]  = r.y;
        sD0[i] = last_coors[r.x * 3 + 0] - cur_coors[r.y * 3 + 0];
        sD1[i] = last_coors[r.x * 3 + 1] - cur_coors[r.y * 3 + 1];
        sD2[i] = last_coors[r.x * 3 + 2] - cur_coors[r.y * 3 + 2];
    }
    __syncthreads();

    const int t = tid;
    const bool active = (t < 300);
    const float sgn = (active && g1[t] < 0.f) ? -1.f : 1.f;
    const float w0 = active ? sWc0[t] : 0.f;
    const float w1 = active ? sWc1[t] : 0.f;
    const float w2 = active ? sWc2[t] : 0.f;

    int cur = (ecnt > 0) ? sCi[0] : 0;
    float m = -3.4e38f, sum = 0.f, sq = 0.f;

    int i = 0;
    for (; i + UNR <= ecnt; i += UNR) {
        float g[UNR];
        #pragma unroll
        for (int j = 0; j < UNR; ++j)
            g[j] = active ? (float)Gb[sRow[i + j] + t] : 0.f;   // 8 loads in flight
        #pragma unroll
        for (int j = 0; j < UNR; ++j) {
            const int ci = sCi[i + j];
            if (ci != cur) {                   // block-uniform branch
                if (active) atomicMax(&zbuf[(long)cur * 300 + t], enc_f32(m));
                cur = ci;
                m = -3.4e38f;
            }
            float y = fmaxf(g[j] + sD0[i + j] * w0 + sD1[i + j] * w1 + sD2[i + j] * w2, 0.f);
            sum += y; sq += y * y;
            m = fmaxf(m, sgn * y);
        }
    }
    for (; i < ecnt; ++i) {
        const int ci = sCi[i];
        if (ci != cur) {
            if (active) atomicMax(&zbuf[(long)cur * 300 + t], enc_f32(m));
            cur = ci;
            m = -3.4e38f;
        }
        float y = active ? (float)Gb[sRow[i] + t] : 0.f;
        y = fmaxf(y + sD0[i] * w0 + sD1[i] * w1 + sD2[i] * w2, 0.f);
        sum += y; sq += y * y;
        m = fmaxf(m, sgn * y);
    }
    if (active && ecnt > 0)
        atomicMax(&zbuf[(long)cur * 300 + t], enc_f32(m));

    const int slot = blockIdx.x & (NPART - 1);
    if (active) {
        atomicAdd(&part1[slot * 600 + t], sum);
        atomicAdd(&part1[slot * 600 + 300 + t], sq);
    }
}

// ---------- reduce partials -> per-feature affine (a, c) ----------
__global__ void stats_finalize(const float* __restrict__ part,
                               const float* __restrict__ g,
                               const float* __restrict__ be,
                               float invCnt, float* __restrict__ ac)
{
    const int t = threadIdx.x;
    if (t >= 300) return;
    float sum = 0.f, sq = 0.f;
    for (int p = 0; p < NPART; ++p) {
        sum += part[p * 600 + t];
        sq  += part[p * 600 + 300 + t];
    }
    const float mean = sum * invCnt;
    const float var = fmaxf(sq * invCnt - mean * mean, 0.f);
    const float inv = rsqrtf(var + 1e-5f);
    const float a = g[t] * inv;
    ac[t] = a;
    ac[300 + t] = be[t] - mean * a;
}

// ---------- decode zbuf [N_cur][300] -> Ab2 bf16 [N_cur][320] zero-padded ----------
__global__ void agg_finalize(const unsigned* __restrict__ zbuf,
                             const float* __restrict__ ac1,
                             bf16_t* __restrict__ Ab2)
{
    const int t = threadIdx.x;   // 320 threads
    float v = 0.f;
    if (t < 300) {
        const unsigned u = zbuf[(long)blockIdx.x * 300 + t];
        if (u != 0u) v = fabsf(ac1[t]) * dec_f32(u) + ac1[300 + t];
    }
    Ab2[(long)blockIdx.x * 320 + t] = (bf16_t)v;
}

// ---------- apply BN2 affine to d_out in place ----------
__global__ void finalize_out(float* __restrict__ out,
                             const float* __restrict__ ac2)
{
    const int t = threadIdx.x;
    if (t >= 300) return;
    const long i = (long)blockIdx.x * 300 + t;
    out[i] = ac2[t] * out[i] + ac2[300 + t];
}

extern "C" void kernel_launch(void* const* d_in, const int* in_sizes, int n_in,
                              void* d_out, int out_size, void* d_ws, size_t ws_size,
                              hipStream_t stream)
{
    const float* last_coors    = (const float*)d_in[0];
    const float* last_features = (const float*)d_in[1];
    const float* cur_coors     = (const float*)d_in[2];
    const int*   cur_idx       = (const int*)d_in[3];
    const int*   last_idx      = (const int*)d_in[4];
    const float* W1  = (const float*)d_in[5];
    const float* b1  = (const float*)d_in[6];
    const float* g1  = (const float*)d_in[7];
    const float* be1 = (const float*)d_in[8];
    const float* W2  = (const float*)d_in[9];
    const float* b2  = (const float*)d_in[10];
    const float* g2  = (const float*)d_in[11];
    const float* be2 = (const float*)d_in[12];
    float* out = (float*)d_out;

    const int N_last = in_sizes[0] / 3;
    const int N_cur  = in_sizes[2] / 3;
    const int E      = in_sizes[3];

    const int nb1 = (N_cur + SB - 1) / SB;

    // ---- workspace ----
    char* ws = (char*)d_ws;
    size_t off = 0;
    // region0: Gb (N_last x 320 bf16) -> later Ab2 (N_cur x 320 bf16)
    bf16_t* Gb  = (bf16_t*)(ws + off);
    bf16_t* Ab2 = (bf16_t*)(ws + off);
    off += (size_t)N_last * 320 * 2; off = (off + 255) & ~(size_t)255;
    unsigned* zbuf = (unsigned*)(ws + off);
    off += (size_t)N_cur * 300 * 4;  off = (off + 255) & ~(size_t)255;
    int2* sorted = (int2*)(ws + off);  off += (size_t)E * 8;
    int* hist = (int*)(ws + off);      off += (size_t)nb1 * SB * 4;
    int* cnt  = (int*)(ws + off);      off += (size_t)nb1 * SB * 4;
    int* bsum = (int*)(ws + off);      off += 256 * 4;
    bf16_t* WT1 = (bf16_t*)(ws + off); off += (size_t)384 * 320 * 2;
    bf16_t* WT2 = (bf16_t*)(ws + off); off += (size_t)384 * 320 * 2;
    float* part1 = (float*)(ws + off); off += (size_t)NPART * 600 * 4;
    float* part2 = (float*)(ws + off); off += (size_t)NPART * 600 * 4;
    float* ac1   = (float*)(ws + off); off += 600 * 4;
    float* ac2   = (float*)(ws + off); off += 600 * 4;

    hipMemsetAsync(zbuf, 0, (size_t)N_cur * 300 * 4, stream);
    hipMemsetAsync(hist, 0, (size_t)nb1 * SB * 4, stream);
    hipMemsetAsync(part1, 0, (size_t)NPART * 600 * 4, stream);
    hipMemsetAsync(part2, 0, (size_t)NPART * 600 * 4, stream);

    // ---- counting sort of edges by cur_idx ----
    hist_k<<<(E + 255) / 256, 256, 0, stream>>>(cur_idx, E, hist);
    scan_reduce<<<nb1, SB, 0, stream>>>(hist, N_cur, bsum);
    scan_top<<<1, SB, 0, stream>>>(bsum, nb1);
    scan_final<<<nb1, SB, 0, stream>>>(hist, N_cur, bsum, cnt);
    scatter_k<<<(E + 255) / 256, 256, 0, stream>>>(cur_idx, last_idx, E, cnt, sorted);

    // ---- weights ----
    pack_wt<<<480, 256, 0, stream>>>(W1, WT1);
    pack_wt<<<480, 256, 0, stream>>>(W2, WT2);

    // G = last_features @ W1[:300] + b1  (fp32 A staged+cvt in-kernel, writes Gb[.,320])
    dim3 gridG((N_last + 127) / 128, 2);
    gemm_mfma<0><<<gridG, 256, 0, stream>>>(last_features, N_last, WT1, b1,
                                            Gb, nullptr, nullptr);

    // edge pass over sorted edges
    const int nEB = (E + CH - 1) / CH;
    edge_pass<<<nEB, 320, 0, stream>>>(Gb, last_coors, cur_coors, sorted,
                                       W1 + 300 * 300, g1, zbuf, part1, E);

    stats_finalize<<<1, 320, 0, stream>>>(part1, g1, be1, 1.0f / (float)E, ac1);
    // Ab2 overwrites Gb (Gb consumed by edge_pass)
    agg_finalize<<<N_cur, 320, 0, stream>>>(zbuf, ac1, Ab2);

    // out_pre = ReLU(agg @ W2 + b2), stats2 partials (bf16 A)
    dim3 grid2((N_cur + 127) / 128, 2);
    gemm_mfma<1><<<grid2, 256, 0, stream>>>(Ab2, N_cur, WT2, b2, nullptr, out, part2);

    stats_finalize<<<1, 320, 0, stream>>>(part2, g2, be2, 1.0f / (float)N_cur, ac2);
    finalize_out<<<N_cur, 320, 0, stream>>>(out, ac2);
}